// Round 20
// baseline (421.744 us; speedup 1.0000x reference)
//
#include <hip/hip_runtime.h>
#include <hip/hip_bf16.h>

typedef __attribute__((ext_vector_type(8))) short short8;
typedef __attribute__((ext_vector_type(4))) float floatx4;
typedef __attribute__((ext_vector_type(16))) float floatx16;

__device__ __forceinline__ unsigned short f2bf(float x) {
  __hip_bfloat16 h = __float2bfloat16(x);
  return __builtin_bit_cast(unsigned short, h);
}
__device__ __forceinline__ float bf2f(unsigned short u) {
  return __builtin_bit_cast(float, (unsigned int)u << 16);
}

// ---------------------------------------------------------------------
// X (fp32) -> bf16 copy
// ---------------------------------------------------------------------
__global__ __launch_bounds__(256) void cvt_x_kernel(
    const float* __restrict__ X, unsigned short* __restrict__ Xbf, int n) {
  int i = blockIdx.x * 256 + threadIdx.x;
  if (i < n) Xbf[i] = f2bf(X[i]);
}

// ---------------------------------------------------------------------
// Pack extended weights [W | root] into MFMA B-fragment order.
// K2=0 packs just a 64x64 matrix from `root`.
// ---------------------------------------------------------------------
__global__ __launch_bounds__(256) void pack_b_kernel(
    const float* __restrict__ W, const float* __restrict__ root,
    unsigned short* __restrict__ Bpk, int K2) {
  int R = (K2 + 1) * 64;
  int total = 64 * R;
  int i = blockIdx.x * 256 + threadIdx.x;
  if (i >= total) return;
  int j = i & 7;
  int lane = (i >> 3) & 63;
  int rest = i >> 9;            // kc*4 + wv
  int wv = rest & 3, kc = rest >> 2;
  int o = wv * 16 + (lane & 15);
  int r = kc * 32 + ((lane >> 4) & 3) * 8 + j;
  int k = r >> 6, d = r & 63;
  float v = (k < K2) ? W[(k << 12) + (d << 6) + o] : root[(d << 6) + o];
  Bpk[i] = f2bf(v);
}

// ---------------------------------------------------------------------
// CSR build (padded to 16-edge chunks per node)
// ---------------------------------------------------------------------
__global__ __launch_bounds__(256) void zero_int_kernel(int* __restrict__ p, int n) {
  int i = blockIdx.x * 256 + threadIdx.x;
  if (i < n) p[i] = 0;
}

__global__ __launch_bounds__(256) void hist_kernel(
    const int* __restrict__ dst, int* __restrict__ deg, int nE) {
  int e = blockIdx.x * 256 + threadIdx.x;
  if (e < nE) atomicAdd(&deg[dst[e]], 1);
}

__global__ __launch_bounds__(256) void blocksum_kernel(
    const int* __restrict__ deg, int* __restrict__ partial, int N) {
  __shared__ int s[256];
  int t = threadIdx.x, i = blockIdx.x * 256 + t;
  s[t] = (i < N) ? ((deg[i] + 15) & ~15) : 0;   // padded degree
  __syncthreads();
  for (int off = 128; off > 0; off >>= 1) {
    if (t < off) s[t] += s[t + off];
    __syncthreads();
  }
  if (t == 0) partial[blockIdx.x] = s[0];
}

__global__ __launch_bounds__(256) void scanpartials_kernel(
    int* __restrict__ partial, int nb) {
  __shared__ int s[256];
  int t = threadIdx.x;
  int v = (t < nb) ? partial[t] : 0;
  s[t] = v;
  __syncthreads();
  for (int off = 1; off < 256; off <<= 1) {
    int x = (t >= off) ? s[t - off] : 0;
    __syncthreads();
    s[t] += x;
    __syncthreads();
  }
  if (t < nb) partial[t] = s[t] - v;
}

__global__ __launch_bounds__(256) void blockscan_kernel(
    const int* __restrict__ deg, const int* __restrict__ partial,
    int* __restrict__ prow, int* __restrict__ cursor, int N) {
  __shared__ int s[256];
  int t = threadIdx.x, i = blockIdx.x * 256 + t;
  int v = (i < N) ? ((deg[i] + 15) & ~15) : 0;
  s[t] = v;
  __syncthreads();
  for (int off = 1; off < 256; off <<= 1) {
    int x = (t >= off) ? s[t - off] : 0;
    __syncthreads();
    s[t] += x;
    __syncthreads();
  }
  if (i < N) {
    int excl = s[t] - v + partial[blockIdx.x];
    prow[i] = excl;
    cursor[i] = excl;
    if (i == N - 1) prow[N] = excl + v;
  }
}

// ---------------------------------------------------------------------
// Scatter: per edge write offs + raw attr (12B scattered — cheap).
// Pad slots are pre-initialized by hipMemsetAsync: offs=0 (safe gather),
// attr2=0xBFBFBFBF (negative float -> sentinel -> zero coefficients).
// ---------------------------------------------------------------------
__global__ __launch_bounds__(256) void scatter_rec_kernel(
    const int* __restrict__ dst, const int* __restrict__ src,
    const float* __restrict__ attr, int* __restrict__ cursor,
    int* __restrict__ offs, float2* __restrict__ attr2, int nE) {
  int e = blockIdx.x * 256 + threadIdx.x;
  if (e >= nE) return;
  int pos = atomicAdd(&cursor[dst[e]], 1);
  offs[pos] = src[e] * 64;
  attr2[pos] = *(const float2*)&attr[2 * e];
}

// ---------------------------------------------------------------------
// Sparse coefficient build: block = 16 chunks x 16 edge-slots.
// Zeroed LDS tile = default coefficient; each thread scatter-writes its
// edge's 4 nonzero products per K into race-free LDS slots; coalesced
// block flush. (R18 dense build: 83us @76% VALU -> this: VALU-light.)
// ---------------------------------------------------------------------
__global__ __launch_bounds__(256) void coeff_build_kernel(
    const float2* __restrict__ attr2, const int* __restrict__ prow,
    unsigned short* __restrict__ cT3, unsigned short* __restrict__ cT5,
    int N) {
  __shared__ unsigned short t5[16 * 512];
  __shared__ unsigned short t3[16 * 256];
  const int t = threadIdx.x;
  const int PE = prow[N];

  for (int i = t; i < 4096; i += 256) ((int*)t5)[i] = 0;
  for (int i = t; i < 2048; i += 256) ((int*)t3)[i] = 0;
  __syncthreads();

  const int chunkL = t >> 4, kp = t & 15;
  const int pos = (blockIdx.x * 16 + chunkL) * 16 + kp;
  if (pos < PE) {
    float2 a = attr2[pos];
    if (a.x >= 0.f) {
      {  // K=5
        float u = a.x * 4.f, v = a.y * 4.f;
        int l0 = min((int)u, 3), l1 = min((int)v, 3);
        float f0 = u - (float)l0, f1 = v - (float)l1;
        float s0 = 1.f - f0, s1 = 1.f - f1;
        unsigned short* b = &t5[chunkL * 512 + kp];
        b[(l0 + l1 * 5) * 16]       = f2bf(s0 * s1);
        b[(l0 + 1 + l1 * 5) * 16]   = f2bf(f0 * s1);
        b[(l0 + (l1 + 1) * 5) * 16] = f2bf(s0 * f1);
        b[(l0 + 1 + (l1 + 1) * 5) * 16] = f2bf(f0 * f1);
      }
      {  // K=3
        float u = a.x * 2.f, v = a.y * 2.f;
        int l0 = min((int)u, 1), l1 = min((int)v, 1);
        float f0 = u - (float)l0, f1 = v - (float)l1;
        float s0 = 1.f - f0, s1 = 1.f - f1;
        unsigned short* b = &t3[chunkL * 256 + kp];
        b[(l0 + l1 * 3) * 16]       = f2bf(s0 * s1);
        b[(l0 + 1 + l1 * 3) * 16]   = f2bf(f0 * s1);
        b[(l0 + (l1 + 1) * 3) * 16] = f2bf(s0 * f1);
        b[(l0 + 1 + (l1 + 1) * 3) * 16] = f2bf(f0 * f1);
      }
    }
  }
  __syncthreads();

  {
    floatx4* dst = (floatx4*)&cT5[(size_t)blockIdx.x * 16 * 512];
    const floatx4* srcp = (const floatx4*)t5;
#pragma unroll
    for (int k = 0; k < 4; ++k) dst[t + k * 256] = srcp[t + k * 256];
  }
  {
    floatx4* dst = (floatx4*)&cT3[(size_t)blockIdx.x * 16 * 256];
    const floatx4* srcp = (const floatx4*)t3;
#pragma unroll
    for (int k = 0; k < 2; ++k) dst[t + k * 256] = srcp[t + k * 256];
  }
}

// ---------------------------------------------------------------------
// FUSED spline layer: block = 4 waves = 16 dst nodes.
// Phase 1: TWO nodes interleaved per pass with separated load/gather/MFMA
//   stages — node1's loads are in flight while node0's MFMA waits
//   (in-order vmcnt), ~2x fewer exposed memory round-trips vs serial.
// Phase 2: out[16x64] = ELU([Az | X] @ Bpk + b); root row read from input.
// ---------------------------------------------------------------------
template <int K, int K2, int OUTBF>
__global__ __launch_bounds__(256) void spline_layer_kernel(
    const unsigned short* __restrict__ cT, const int* __restrict__ offs,
    const int* __restrict__ prow, const int* __restrict__ deg,
    const unsigned short* __restrict__ Xbf, const unsigned short* __restrict__ Bpk,
    const float* __restrict__ bias, void* __restrict__ outv, int N) {
  constexpr int RZ = K2 * 64;          // bucket columns: 576 / 1600
  constexpr int AS = RZ + 8;           // LDS row stride (shorts)
  constexpr int NKZ = RZ / 32;         // 18 / 50
  constexpr int NKC = (K2 + 1) * 2;    // 20 / 52
  constexpr int CSTRIDE = (K == 3) ? 256 : 512;
  __shared__ unsigned short As[16 * AS];
  const int t = threadIdx.x, w = t >> 6, lane = t & 63;
  const int nodeBase = blockIdx.x * 16;

  const int col = lane & 31, half = lane >> 5;

  // ---------- phase 1: 2 passes x 2 interleaved nodes per wave ----------
  for (int p = 0; p < 2; ++p) {
    const int row0 = w * 4 + p * 2;
    const int nodeA = nodeBase + row0, nodeB = nodeA + 1;
    int begA = 0, ncA = 0, begB = 0, ncB = 0;
    if (nodeA < N) { begA = prow[nodeA]; ncA = (prow[nodeA + 1] - begA) >> 4; }
    if (nodeB < N) { begB = prow[nodeB]; ncB = (prow[nodeB + 1] - begB) >> 4; }

    floatx16 dA0, dA1, dB0, dB1;
#pragma unroll
    for (int i = 0; i < 16; ++i) { dA0[i] = 0.f; dA1[i] = 0.f; dB0[i] = 0.f; dB1[i] = 0.f; }

    const int ncm = max(ncA, ncB);
    for (int it = 0; it < ncm; ++it) {
      const bool aA = it < ncA, aB = it < ncB;   // wave-uniform
      short8 A0 = {0,0,0,0,0,0,0,0}, A1 = {0,0,0,0,0,0,0,0};
      int oA[8], oB[8];
      // stage 1: A-frag + offs loads for both nodes (independent)
      if (aA) {
        const int chunk = (begA >> 4) + it;
        if (K == 3) {
          short8 tmp = *(const short8*)&cT[(size_t)chunk * CSTRIDE + (col & 15) * 16 + half * 8];
          short8 zero = {0,0,0,0,0,0,0,0};
          A0 = (col < 16) ? tmp : zero;
        } else {
          A0 = *(const short8*)&cT[(size_t)chunk * CSTRIDE + col * 16 + half * 8];
        }
#pragma unroll
        for (int j = 0; j < 8; ++j) oA[j] = offs[chunk * 16 + half * 8 + j];
      }
      if (aB) {
        const int chunk = (begB >> 4) + it;
        if (K == 3) {
          short8 tmp = *(const short8*)&cT[(size_t)chunk * CSTRIDE + (col & 15) * 16 + half * 8];
          short8 zero = {0,0,0,0,0,0,0,0};
          A1 = (col < 16) ? tmp : zero;
        } else {
          A1 = *(const short8*)&cT[(size_t)chunk * CSTRIDE + col * 16 + half * 8];
        }
#pragma unroll
        for (int j = 0; j < 8; ++j) oB[j] = offs[chunk * 16 + half * 8 + j];
      }
      // stage 2: gathers for both nodes
      short8 BloA, BhiA, BloB, BhiB;
      if (aA) {
#pragma unroll
        for (int j = 0; j < 8; ++j) {
          BloA[j] = (short)Xbf[oA[j] + col];
          BhiA[j] = (short)Xbf[oA[j] + 32 + col];
        }
      }
      if (aB) {
#pragma unroll
        for (int j = 0; j < 8; ++j) {
          BloB[j] = (short)Xbf[oB[j] + col];
          BhiB[j] = (short)Xbf[oB[j] + 32 + col];
        }
      }
      // stage 3: MFMAs
      if (aA) {
        dA0 = __builtin_amdgcn_mfma_f32_32x32x16_bf16(A0, BloA, dA0, 0, 0, 0);
        dA1 = __builtin_amdgcn_mfma_f32_32x32x16_bf16(A0, BhiA, dA1, 0, 0, 0);
      }
      if (aB) {
        dB0 = __builtin_amdgcn_mfma_f32_32x32x16_bf16(A1, BloB, dB0, 0, 0, 0);
        dB1 = __builtin_amdgcn_mfma_f32_32x32x16_bf16(A1, BhiB, dB1, 0, 0, 0);
      }
    }

    // write-back both nodes to LDS
    if (nodeA < N) {
      const float inv = 1.f / (float)max(deg[nodeA], 1);
#pragma unroll
      for (int reg = 0; reg < 16; ++reg) {
        int r = (reg & 3) + 8 * (reg >> 2) + 4 * half;
        if (r < K2) {
          As[row0 * AS + r * 64 + col] = f2bf(dA0[reg] * inv);
          As[row0 * AS + r * 64 + 32 + col] = f2bf(dA1[reg] * inv);
        }
      }
    } else {
      for (int i = lane; i < RZ; i += 64) As[row0 * AS + i] = 0;
    }
    if (nodeB < N) {
      const float inv = 1.f / (float)max(deg[nodeB], 1);
#pragma unroll
      for (int reg = 0; reg < 16; ++reg) {
        int r = (reg & 3) + 8 * (reg >> 2) + 4 * half;
        if (r < K2) {
          As[(row0 + 1) * AS + r * 64 + col] = f2bf(dB0[reg] * inv);
          As[(row0 + 1) * AS + r * 64 + 32 + col] = f2bf(dB1[reg] * inv);
        }
      }
    } else {
      for (int i = lane; i < RZ; i += 64) As[(row0 + 1) * AS + i] = 0;
    }
  }
  __syncthreads();

  // ---------- phase 2: 16 x R x 64 GEMM + bias + ELU ----------
  const int mrow = lane & 15, q = lane >> 4;
  const int anode = min(nodeBase + mrow, N - 1);  // root row (clamped; garbage
                                                  // only hits discarded rows)
  floatx4 acc = {0.f, 0.f, 0.f, 0.f};
#pragma unroll
  for (int kc = 0; kc < NKC; ++kc) {
    short8 a;
    if (kc < NKZ)
      a = *(const short8*)&As[mrow * AS + kc * 32 + q * 8];
    else
      a = *(const short8*)&Xbf[(size_t)anode * 64 + (kc - NKZ) * 32 + q * 8];
    short8 b = *(const short8*)&Bpk[(((size_t)kc * 4 + w) * 64 + lane) * 8];
    acc = __builtin_amdgcn_mfma_f32_16x16x32_bf16(a, b, acc, 0, 0, 0);
  }

  const int o = w * 16 + mrow;
  const float bv = bias[o];
#pragma unroll
  for (int reg = 0; reg < 4; ++reg) {
    int node = nodeBase + q * 4 + reg;
    if (node < N) {
      float v = acc[reg] + bv;
      v = v > 0.f ? v : (expf(v) - 1.f);
      if (OUTBF)
        ((unsigned short*)outv)[(size_t)node * 64 + o] = f2bf(v);
      else
        ((float*)outv)[(size_t)node * 64 + o] = v;
    }
  }
}

// ---------------------------------------------------------------------
// FUSED MLP head: out = relu( relu(h2 @ m1w + m1b) @ m2w + m2b )
// ---------------------------------------------------------------------
__global__ __launch_bounds__(256) void head_kernel(
    const unsigned short* __restrict__ h2bf, const unsigned short* __restrict__ m1pk,
    const float* __restrict__ m1b, const float* __restrict__ m2w,
    const float* __restrict__ m2b, float* __restrict__ out, int N) {
  __shared__ unsigned short Hs[64 * 72];
  __shared__ unsigned short Ts[64 * 72];
  __shared__ float W2s[512];
  const int t = threadIdx.x, w = t >> 6, lane = t & 63;
  const int n0 = blockIdx.x * 64;

  for (int i = t; i < 512; i += 256) {
    int row = i >> 3, cg = i & 7;
    int n = n0 + row;
    floatx4 val = {0.f, 0.f, 0.f, 0.f};
    if (n < N) val = *(const floatx4*)&h2bf[(size_t)n * 64 + cg * 8];
    *(floatx4*)&Hs[row * 72 + cg * 8] = val;
  }
  for (int i = t; i < 512; i += 256) W2s[i] = m2w[i];
  __syncthreads();

  const int mrow = lane & 15, q = lane >> 4;
  const int o = w * 16 + mrow;
  const float bv = m1b[o];
#pragma unroll
  for (int rg = 0; rg < 4; ++rg) {
    floatx4 acc = {0.f, 0.f, 0.f, 0.f};
#pragma unroll
    for (int kc = 0; kc < 2; ++kc) {
      short8 a = *(const short8*)&Hs[(rg * 16 + mrow) * 72 + kc * 32 + q * 8];
      short8 b = *(const short8*)&m1pk[(((size_t)kc * 4 + w) * 64 + lane) * 8];
      acc = __builtin_amdgcn_mfma_f32_16x16x32_bf16(a, b, acc, 0, 0, 0);
    }
#pragma unroll
    for (int reg = 0; reg < 4; ++reg) {
      int row = rg * 16 + q * 4 + reg;
      float v = acc[reg] + bv;
      Ts[row * 72 + o] = f2bf(v > 0.f ? v : 0.f);
    }
  }
  __syncthreads();

  for (int i = t; i < 512; i += 256) {
    int nl = i >> 3, c = i & 7;
    int n = n0 + nl;
    if (n >= N) continue;
    float s = m2b[c];
    for (int d = 0; d < 64; ++d) s += bf2f(Ts[nl * 72 + d]) * W2s[d * 8 + c];
    out[(size_t)n * 8 + c] = s > 0.f ? s : 0.f;
  }
}

// ---------------------------------------------------------------------
extern "C" void kernel_launch(void* const* d_in, const int* in_sizes, int n_in,
                              void* d_out, int out_size, void* d_ws, size_t ws_size,
                              hipStream_t stream) {
  const float* x     = (const float*)d_in[0];
  const int*   ei    = (const int*)d_in[1];
  const float* attr  = (const float*)d_in[2];
  const float* W1    = (const float*)d_in[3];
  const float* root1 = (const float*)d_in[4];
  const float* b1    = (const float*)d_in[5];
  const float* W2    = (const float*)d_in[6];
  const float* root2 = (const float*)d_in[7];
  const float* b2    = (const float*)d_in[8];
  const float* m1w   = (const float*)d_in[9];
  const float* m1b   = (const float*)d_in[10];
  const float* m2w   = (const float*)d_in[11];
  const float* m2b   = (const float*)d_in[12];

  const int N  = in_sizes[0] / 64;
  const int nE = in_sizes[1] / 2;
  const int* src  = ei;
  const int* dstv = ei + nE;
  float* out = (float*)d_out;

  // workspace layout
  const size_t maxPE = (size_t)nE + 16 * (size_t)N;      // padded-edge bound
  const size_t maxChunks = (maxPE / 16 + 15) & ~(size_t)15;  // 16-aligned
  int* deg     = (int*)d_ws;
  int* prow    = deg + N;                 // N+1
  int* cursor  = prow + (N + 1);
  int* partial = cursor + N;              // 256
  char* pbase = (char*)(partial + 256);
  pbase = (char*)(((uintptr_t)pbase + 15) & ~(uintptr_t)15);
  int* offs = (int*)pbase;                                // maxPE
  float2* attr2 = (float2*)(offs + maxPE);                // maxPE * 8B
  unsigned short* cT3 = (unsigned short*)(attr2 + maxPE); // maxChunks*256
  unsigned short* cT5 = cT3 + maxChunks * 256;            // maxChunks*512
  unsigned short* Xbf  = cT5 + maxChunks * 512;           // N*64
  unsigned short* h1bf = Xbf + (size_t)N * 64;            // N*64
  unsigned short* h2bf = h1bf + (size_t)N * 64;           // N*64
  unsigned short* Bpk1 = h2bf + (size_t)N * 64;           // 64*640
  unsigned short* Bpk2 = Bpk1 + 64 * 640;                 // 64*1664
  unsigned short* m1pk = Bpk2 + 64 * 1664;                // 64*64

  dim3 blk(256);
  int nbN  = (N + 255) / 256;
  int nbE  = (nE + 255) / 256;
  int nbC  = (int)(maxChunks / 16);
  int nbF  = (N + 15) / 16;
  int nbH  = (N + 63) / 64;

  // ----- CSR build (padded; graph identical both layers) -----
  zero_int_kernel<<<nbN, blk, 0, stream>>>(deg, N);
  hist_kernel<<<nbE, blk, 0, stream>>>(dstv, deg, nE);
  blocksum_kernel<<<nbN, blk, 0, stream>>>(deg, partial, N);
  scanpartials_kernel<<<1, blk, 0, stream>>>(partial, nbN);
  blockscan_kernel<<<nbN, blk, 0, stream>>>(deg, partial, prow, cursor, N);
  // pad defaults: offs=0 (safe gather), attr2=0xBFBF.. (<0 sentinel -> coeff 0)
  (void)hipMemsetAsync(offs, 0, maxPE * sizeof(int), stream);
  (void)hipMemsetAsync(attr2, 0xBF, maxPE * sizeof(float2), stream);
  scatter_rec_kernel<<<nbE, blk, 0, stream>>>(dstv, src, attr, cursor,
                                              offs, attr2, nE);
  coeff_build_kernel<<<nbC, blk, 0, stream>>>(attr2, prow, cT3, cT5, N);

  // ----- weight / input prep -----
  pack_b_kernel<<<(64 * 640 + 255) / 256, blk, 0, stream>>>(W1, root1, Bpk1, 9);
  pack_b_kernel<<<(64 * 1664 + 255) / 256, blk, 0, stream>>>(W2, root2, Bpk2, 25);
  pack_b_kernel<<<(64 * 64 + 255) / 256, blk, 0, stream>>>(m1w, m1w, m1pk, 0);
  cvt_x_kernel<<<(N * 64 + 255) / 256, blk, 0, stream>>>(x, Xbf, N * 64);

  // ----- layer 1 (K=3, K2=9): fused zbuild+GEMM, bf16 out -----
  spline_layer_kernel<3, 9, 1><<<nbF, blk, 0, stream>>>(
      cT3, offs, prow, deg, Xbf, Bpk1, b1, h1bf, N);

  // ----- layer 2 (K=5, K2=25): fused zbuild+GEMM, bf16 out -----
  spline_layer_kernel<5, 25, 1><<<nbF, blk, 0, stream>>>(
      cT5, offs, prow, deg, h1bf, Bpk2, b2, h2bf, N);

  // ----- fused MLP head -----
  head_kernel<<<nbH, blk, 0, stream>>>(h2bf, m1pk, m1b, m2w, m2b, out, N);
}